// Round 1
// baseline (810.160 us; speedup 1.0000x reference)
//
#include <hip/hip_runtime.h>

// Causal self-attention fwd: B=2,T=2048,C=1024,H=16,D=64, scale=0.1/sqrt(D)
// Pipeline: cast x->bf16; transpose+cast weights; qkv = x@w_attn+b (MFMA bf16,
// bf16 out); flash attention (fp32 LDS, online softmax) -> y bf16;
// out = y@w_proj+b (MFMA bf16, fp32 out).

#define Bz 2
#define Tz 2048
#define Cz 1024
#define Hz 16
#define Dz 64
#define SCALEF 0.0125f

typedef unsigned short u16;
typedef short bf16x8 __attribute__((ext_vector_type(8)));
typedef float f32x4 __attribute__((ext_vector_type(4)));

__device__ inline u16 f2bf(float f) {
  unsigned u = __float_as_uint(f);
  u += 0x7fffu + ((u >> 16) & 1u);   // round-to-nearest-even
  return (u16)(u >> 16);
}

__device__ inline void unpack8(uint4 u, float* dst) {
  unsigned w[4] = {u.x, u.y, u.z, u.w};
#pragma unroll
  for (int q = 0; q < 4; ++q) {
    dst[2 * q]     = __uint_as_float(w[q] << 16);
    dst[2 * q + 1] = __uint_as_float(w[q] & 0xffff0000u);
  }
}

// ---------------- cast fp32 -> bf16, float4-vectorized ----------------
__global__ void cast_kernel(const float* __restrict__ in, u16* __restrict__ out, int n4) {
  int i = blockIdx.x * blockDim.x + threadIdx.x;
  if (i >= n4) return;
  float4 v = ((const float4*)in)[i];
  ushort4 o = {f2bf(v.x), f2bf(v.y), f2bf(v.z), f2bf(v.w)};
  ((ushort4*)out)[i] = o;
}

// ---------- W[K][N] fp32 -> WT[N][K] bf16 (tiled transpose) ----------
__global__ void transpose_cast_kernel(const float* __restrict__ W, u16* __restrict__ WT,
                                      int K, int N) {
  __shared__ float tile[32][33];
  int n0 = blockIdx.x * 32, k0 = blockIdx.y * 32;
  int tx = threadIdx.x, ty = threadIdx.y;  // (32, 8)
#pragma unroll
  for (int i = 0; i < 4; ++i)
    tile[ty + 8 * i][tx] = W[(size_t)(k0 + ty + 8 * i) * N + n0 + tx];
  __syncthreads();
#pragma unroll
  for (int i = 0; i < 4; ++i)
    WT[(size_t)(n0 + ty + 8 * i) * K + k0 + tx] = f2bf(tile[tx][ty + 8 * i]);
}

// ---------- C[M][N] = A[M][K]*BT[N][K]^T + bias, bf16 MFMA ----------
// Block: 256 thr = 4 waves; tile 64x64; BK=32; wave w owns rows [16w,16w+16).
template <bool OUT_BF16>
__global__ __launch_bounds__(256) void gemm_bt(const u16* __restrict__ A,
                                               const u16* __restrict__ BT,
                                               const float* __restrict__ bias,
                                               void* __restrict__ Cout,
                                               int M, int N, int K) {
  __shared__ __align__(16) u16 As[64][40];  // +8 pad keeps 16B align, spreads banks
  __shared__ __align__(16) u16 Bs[64][40];
  const int t = threadIdx.x;
  const int wave = t >> 6, lane = t & 63;
  const int lm = lane & 15, kg8 = (lane >> 4) << 3;
  const int m0 = blockIdx.y * 64, n0 = blockIdx.x * 64;
  const int srow = t >> 2, skseg = (t & 3) << 3;

  f32x4 acc[4];
#pragma unroll
  for (int nt = 0; nt < 4; ++nt)
#pragma unroll
    for (int i = 0; i < 4; ++i) acc[nt][i] = 0.f;

  for (int k0 = 0; k0 < K; k0 += 32) {
    __syncthreads();
    *(uint4*)&As[srow][skseg] = *(const uint4*)(A + (size_t)(m0 + srow) * K + k0 + skseg);
    *(uint4*)&Bs[srow][skseg] = *(const uint4*)(BT + (size_t)(n0 + srow) * K + k0 + skseg);
    __syncthreads();
    bf16x8 af = *(const bf16x8*)&As[(wave << 4) + lm][kg8];
#pragma unroll
    for (int nt = 0; nt < 4; ++nt) {
      bf16x8 bf = *(const bf16x8*)&Bs[(nt << 4) + lm][kg8];
      acc[nt] = __builtin_amdgcn_mfma_f32_16x16x32_bf16(af, bf, acc[nt], 0, 0, 0);
    }
  }

  const int r4 = (lane >> 4) << 2;
#pragma unroll
  for (int nt = 0; nt < 4; ++nt) {
    int gc = n0 + (nt << 4) + lm;
    float bv = bias[gc];
#pragma unroll
    for (int i = 0; i < 4; ++i) {
      int gr = m0 + (wave << 4) + r4 + i;
      float v = acc[nt][i] + bv;
      if (OUT_BF16)
        ((u16*)Cout)[(size_t)gr * N + gc] = f2bf(v);
      else
        ((float*)Cout)[(size_t)gr * N + gc] = v;
    }
  }
}

// ---------------- flash attention, fp32, online softmax ----------------
// Grid: (T/64, B*H). Block 256 = (tx 0..15, ty 0..15).
// Thread owns rows r_i = ty+16i, cols/d c_j = tx+16j (4x4 micro-tile).
// KPs doubles as K-tile then P-tile (stay under 64KB static LDS).
__global__ __launch_bounds__(256) void attn_kernel(const u16* __restrict__ qkv,
                                                   u16* __restrict__ yb) {
  __shared__ float Qs[64][65];
  __shared__ float KPs[64][65];
  __shared__ float Vs[64][65];
  const int t = threadIdx.x;
  const int tx = t & 15, ty = t >> 4;
  const int qt = blockIdx.x, bh = blockIdx.y;
  const int b = bh >> 4, h = bh & 15;
  const int q0 = qt * 64;
  const size_t rowstride = 3 * Cz;
  const size_t base = (size_t)(b * Tz) * rowstride + (size_t)h * Dz;
  const int srow = t >> 2, sdseg = (t & 3) << 4;

  {  // stage Q tile (bf16 -> fp32 LDS)
    const u16* src = qkv + base + (size_t)(q0 + srow) * rowstride + sdseg;
    float tmp[16];
    unpack8(*(const uint4*)src, tmp);
    unpack8(*(const uint4*)(src + 8), tmp + 8);
#pragma unroll
    for (int j = 0; j < 16; ++j) Qs[srow][sdseg + j] = tmp[j];
  }

  float O[4][4], m_run[4], l_run[4];
#pragma unroll
  for (int i = 0; i < 4; ++i) {
    m_run[i] = -1e30f;
    l_run[i] = 0.f;
#pragma unroll
    for (int j = 0; j < 4; ++j) O[i][j] = 0.f;
  }
  __syncthreads();

  for (int kt = 0; kt <= qt; ++kt) {
    const int s0 = kt * 64;
    {  // stage K,V tiles
      const u16* ksrc = qkv + base + Cz + (size_t)(s0 + srow) * rowstride + sdseg;
      const u16* vsrc = qkv + base + 2 * Cz + (size_t)(s0 + srow) * rowstride + sdseg;
      float tmp[16];
      unpack8(*(const uint4*)ksrc, tmp);
      unpack8(*(const uint4*)(ksrc + 8), tmp + 8);
#pragma unroll
      for (int j = 0; j < 16; ++j) KPs[srow][sdseg + j] = tmp[j];
      unpack8(*(const uint4*)vsrc, tmp);
      unpack8(*(const uint4*)(vsrc + 8), tmp + 8);
#pragma unroll
      for (int j = 0; j < 16; ++j) Vs[srow][sdseg + j] = tmp[j];
    }
    __syncthreads();

    // S = Q K^T  (4x4 per thread)
    float S[4][4];
#pragma unroll
    for (int i = 0; i < 4; ++i)
#pragma unroll
      for (int j = 0; j < 4; ++j) S[i][j] = 0.f;
#pragma unroll 4
    for (int d = 0; d < 64; ++d) {
      float qv[4], kv[4];
#pragma unroll
      for (int i = 0; i < 4; ++i) qv[i] = Qs[ty + 16 * i][d];
#pragma unroll
      for (int j = 0; j < 4; ++j) kv[j] = KPs[tx + 16 * j][d];
#pragma unroll
      for (int i = 0; i < 4; ++i)
#pragma unroll
        for (int j = 0; j < 4; ++j) S[i][j] += qv[i] * kv[j];
    }

    // scale + causal mask + online softmax update
    float alpha[4];
#pragma unroll
    for (int i = 0; i < 4; ++i) {
      const int rg = q0 + ty + 16 * i;
      float mx = -1e30f;
#pragma unroll
      for (int j = 0; j < 4; ++j) {
        const int sg = s0 + tx + 16 * j;
        S[i][j] = (sg <= rg) ? S[i][j] * SCALEF : -1e30f;
        mx = fmaxf(mx, S[i][j]);
      }
#pragma unroll
      for (int msk = 1; msk < 16; msk <<= 1) mx = fmaxf(mx, __shfl_xor(mx, msk));
      float mnew = fmaxf(m_run[i], mx);
      alpha[i] = __expf(m_run[i] - mnew);
      m_run[i] = mnew;
      float sum = 0.f;
#pragma unroll
      for (int j = 0; j < 4; ++j) {
        float p = __expf(S[i][j] - mnew);
        S[i][j] = p;
        sum += p;
      }
#pragma unroll
      for (int msk = 1; msk < 16; msk <<= 1) sum += __shfl_xor(sum, msk);
      l_run[i] = l_run[i] * alpha[i] + sum;
#pragma unroll
      for (int j = 0; j < 4; ++j) O[i][j] *= alpha[i];
    }

    __syncthreads();  // all K reads done; safe to overwrite KPs with P
#pragma unroll
    for (int i = 0; i < 4; ++i)
#pragma unroll
      for (int j = 0; j < 4; ++j) KPs[ty + 16 * i][tx + 16 * j] = S[i][j];
    __syncthreads();

    // O += P V
#pragma unroll 4
    for (int s = 0; s < 64; ++s) {
      float pv[4], vv[4];
#pragma unroll
      for (int i = 0; i < 4; ++i) pv[i] = KPs[ty + 16 * i][s];
#pragma unroll
      for (int j = 0; j < 4; ++j) vv[j] = Vs[s][tx + 16 * j];
#pragma unroll
      for (int i = 0; i < 4; ++i)
#pragma unroll
        for (int j = 0; j < 4; ++j) O[i][j] += pv[i] * vv[j];
    }
    __syncthreads();  // PV done before next-tile staging
  }

#pragma unroll
  for (int i = 0; i < 4; ++i) {
    float inv = 1.f / l_run[i];
    const int rg = q0 + ty + 16 * i;
#pragma unroll
    for (int j = 0; j < 4; ++j) {
      int c = h * Dz + tx + 16 * j;
      yb[(size_t)(b * Tz + rg) * Cz + c] = f2bf(O[i][j] * inv);
    }
  }
}

extern "C" void kernel_launch(void* const* d_in, const int* in_sizes, int n_in,
                              void* d_out, int out_size, void* d_ws, size_t ws_size,
                              hipStream_t stream) {
  const float* x      = (const float*)d_in[0];
  const float* w_attn = (const float*)d_in[1];
  const float* b_attn = (const float*)d_in[2];
  const float* w_proj = (const float*)d_in[3];
  const float* b_proj = (const float*)d_in[4];

  char* ws = (char*)d_ws;
  u16* xb   = (u16*)(ws);                        //  8 MB: x bf16 [4096,1024]
  u16* waT  = (u16*)(ws + (8ull << 20));         //  6 MB: w_attn^T bf16 [3072,1024]
  u16* wpT  = (u16*)(ws + (14ull << 20));        //  2 MB: w_proj^T bf16 [1024,1024]
  u16* qkvb = (u16*)(ws + (16ull << 20));        // 24 MB: qkv bf16 [4096,3072]
  u16* yb   = (u16*)(ws + (40ull << 20));        //  8 MB: y bf16 [4096,1024]

  const int M = Bz * Tz;  // 4096

  int n4 = (M * Cz) / 4;
  cast_kernel<<<n4 / 256, 256, 0, stream>>>(x, xb, n4);
  transpose_cast_kernel<<<dim3(3 * Cz / 32, Cz / 32), dim3(32, 8), 0, stream>>>(
      w_attn, waT, Cz, 3 * Cz);
  transpose_cast_kernel<<<dim3(Cz / 32, Cz / 32), dim3(32, 8), 0, stream>>>(
      w_proj, wpT, Cz, Cz);
  gemm_bt<true><<<dim3(3 * Cz / 64, M / 64), 256, 0, stream>>>(
      xb, waT, b_attn, qkvb, M, 3 * Cz, Cz);
  attn_kernel<<<dim3(Tz / 64, Bz * Hz), 256, 0, stream>>>(qkvb, yb);
  gemm_bt<false><<<dim3(Cz / 64, M / 64), 256, 0, stream>>>(
      yb, wpT, b_proj, d_out, M, Cz, Cz);
}

// Round 2
// 291.497 us; speedup vs baseline: 2.7793x; 2.7793x over previous
//
#include <hip/hip_runtime.h>

// Causal self-attention fwd: B=2,T=2048,C=1024,H=16,D=64, scale=0.1/sqrt(D)
// Pipeline: cast x->bf16; transpose+cast weights; qkv = x@w_attn+b (MFMA bf16,
// bf16 out); flash attention with MFMA QK^T / PV (bf16, online softmax);
// out = y@w_proj+b (MFMA bf16, fp32 out).

#define Bz 2
#define Tz 2048
#define Cz 1024
#define Hz 16
#define Dz 64
#define SCALEF 0.0125f

typedef unsigned short u16;
typedef short bf16x8 __attribute__((ext_vector_type(8)));
typedef float f32x4 __attribute__((ext_vector_type(4)));

__device__ inline u16 f2bf(float f) {
  unsigned u = __float_as_uint(f);
  u += 0x7fffu + ((u >> 16) & 1u);   // round-to-nearest-even
  return (u16)(u >> 16);
}

// ---------------- cast fp32 -> bf16, float4-vectorized ----------------
__global__ void cast_kernel(const float* __restrict__ in, u16* __restrict__ out, int n4) {
  int i = blockIdx.x * blockDim.x + threadIdx.x;
  if (i >= n4) return;
  float4 v = ((const float4*)in)[i];
  ushort4 o = {f2bf(v.x), f2bf(v.y), f2bf(v.z), f2bf(v.w)};
  ((ushort4*)out)[i] = o;
}

// ---------- W[K][N] fp32 -> WT[N][K] bf16 (tiled transpose) ----------
__global__ void transpose_cast_kernel(const float* __restrict__ W, u16* __restrict__ WT,
                                      int K, int N) {
  __shared__ float tile[32][33];
  int n0 = blockIdx.x * 32, k0 = blockIdx.y * 32;
  int tx = threadIdx.x, ty = threadIdx.y;  // (32, 8)
#pragma unroll
  for (int i = 0; i < 4; ++i)
    tile[ty + 8 * i][tx] = W[(size_t)(k0 + ty + 8 * i) * N + n0 + tx];
  __syncthreads();
#pragma unroll
  for (int i = 0; i < 4; ++i)
    WT[(size_t)(n0 + ty + 8 * i) * K + k0 + tx] = f2bf(tile[tx][ty + 8 * i]);
}

// ---------- C[M][N] = A[M][K]*BT[N][K]^T + bias, bf16 MFMA ----------
template <bool OUT_BF16>
__global__ __launch_bounds__(256) void gemm_bt(const u16* __restrict__ A,
                                               const u16* __restrict__ BT,
                                               const float* __restrict__ bias,
                                               void* __restrict__ Cout,
                                               int M, int N, int K) {
  __shared__ __align__(16) u16 As[64][40];
  __shared__ __align__(16) u16 Bs[64][40];
  const int t = threadIdx.x;
  const int wave = t >> 6, lane = t & 63;
  const int lm = lane & 15, kg8 = (lane >> 4) << 3;
  const int m0 = blockIdx.y * 64, n0 = blockIdx.x * 64;
  const int srow = t >> 2, skseg = (t & 3) << 3;

  f32x4 acc[4];
#pragma unroll
  for (int nt = 0; nt < 4; ++nt)
#pragma unroll
    for (int i = 0; i < 4; ++i) acc[nt][i] = 0.f;

  for (int k0 = 0; k0 < K; k0 += 32) {
    __syncthreads();
    *(uint4*)&As[srow][skseg] = *(const uint4*)(A + (size_t)(m0 + srow) * K + k0 + skseg);
    *(uint4*)&Bs[srow][skseg] = *(const uint4*)(BT + (size_t)(n0 + srow) * K + k0 + skseg);
    __syncthreads();
    bf16x8 af = *(const bf16x8*)&As[(wave << 4) + lm][kg8];
#pragma unroll
    for (int nt = 0; nt < 4; ++nt) {
      bf16x8 bf = *(const bf16x8*)&Bs[(nt << 4) + lm][kg8];
      acc[nt] = __builtin_amdgcn_mfma_f32_16x16x32_bf16(af, bf, acc[nt], 0, 0, 0);
    }
  }

  const int r4 = (lane >> 4) << 2;
#pragma unroll
  for (int nt = 0; nt < 4; ++nt) {
    int gc = n0 + (nt << 4) + lm;
    float bv = bias[gc];
#pragma unroll
    for (int i = 0; i < 4; ++i) {
      int gr = m0 + (wave << 4) + r4 + i;
      float v = acc[nt][i] + bv;
      if (OUT_BF16)
        ((u16*)Cout)[(size_t)gr * N + gc] = f2bf(v);
      else
        ((float*)Cout)[(size_t)gr * N + gc] = v;
    }
  }
}

// ---------------- flash attention, MFMA bf16 ----------------
// Grid: (32 qtiles swizzled, B*H). Block 256 = 4 waves; wave w owns Q-rows
// [64*qt+16w, +16). K-tile 64. Q frags direct from global; K staged [s][d];
// V staged transposed [d][s] (paired u32 writes, conflict-free); P via
// wave-private LDS C-layout -> A-layout round trip.
__global__ __launch_bounds__(256) void attn_kernel(const u16* __restrict__ qkv,
                                                   u16* __restrict__ yb) {
  __shared__ __align__(16) u16 Ks[64][72];
  __shared__ __align__(16) u16 Vt[64][72];
  __shared__ __align__(16) u16 Ps[64][72];

  const int t = threadIdx.x;
  const int wave = t >> 6, lane = t & 63;
  const int lm = lane & 15, lg = lane >> 4;
  const int kg8 = lg << 3;
  const int bx = blockIdx.x;
  const int qt = (bx & 1) ? (31 - (bx >> 1)) : (bx >> 1);  // pair long+short blocks
  const int bh = blockIdx.y;
  const int b = bh >> 4, h = bh & 15;
  const int q0 = qt * 64;
  const size_t rowstride = 3 * Cz;
  const u16* qbase = qkv + (size_t)b * Tz * rowstride + h * Dz;

  // Q fragments: A-layout = row (q0+16w+lm), k-seg kg8 — direct global uint4
  bf16x8 qf[2];
  {
    const u16* qrow = qbase + (size_t)(q0 + wave * 16 + lm) * rowstride + kg8;
    qf[0] = *(const bf16x8*)qrow;
    qf[1] = *(const bf16x8*)(qrow + 32);
  }

  float m_run[4], l_run[4];
  f32x4 Oa[4];
#pragma unroll
  for (int i = 0; i < 4; ++i) {
    m_run[i] = -1e30f;
    l_run[i] = 0.f;
#pragma unroll
    for (int j = 0; j < 4; ++j) Oa[i][j] = 0.f;
  }

  // staging indices
  const int ksr = t >> 2, kds = (t & 3) << 4;          // K: row, 16-col seg
  const int vsp = t & 31, vds = (t >> 5) << 3;         // V: s-pair, 8-d seg
  const u16* kptr = qbase + Cz + (size_t)ksr * rowstride + kds;
  const u16* vptr = qbase + 2 * Cz + (size_t)(2 * vsp) * rowstride + vds;
  const size_t tilestep = 64 * rowstride;

  for (int kt = 0; kt <= qt; ++kt) {
    __syncthreads();  // prior tile's K/Vt reads complete
    // ---- stage K [s][d] ----
    *(uint4*)&Ks[ksr][kds] = *(const uint4*)kptr;
    *(uint4*)&Ks[ksr][kds + 8] = *(const uint4*)(kptr + 8);
    // ---- stage V transposed [d][s], packed pair writes ----
    {
      uint4 a = *(const uint4*)vptr;
      uint4 c = *(const uint4*)(vptr + rowstride);
      unsigned av[4] = {a.x, a.y, a.z, a.w};
      unsigned cv[4] = {c.x, c.y, c.z, c.w};
#pragma unroll
      for (int j = 0; j < 4; ++j) {
        unsigned w0 = (av[j] & 0xffffu) | (cv[j] << 16);
        unsigned w1 = (av[j] >> 16) | (cv[j] & 0xffff0000u);
        *(unsigned*)&Vt[vds + 2 * j][2 * vsp] = w0;
        *(unsigned*)&Vt[vds + 2 * j + 1][2 * vsp] = w1;
      }
    }
    kptr += tilestep;
    vptr += tilestep;
    __syncthreads();

    // ---- S = Q K^T ----
    f32x4 S[4];
#pragma unroll
    for (int c = 0; c < 4; ++c) {
      bf16x8 k0 = *(const bf16x8*)&Ks[c * 16 + lm][kg8];
      bf16x8 k1 = *(const bf16x8*)&Ks[c * 16 + lm][32 + kg8];
      f32x4 s;
#pragma unroll
      for (int i = 0; i < 4; ++i) s[i] = 0.f;
      s = __builtin_amdgcn_mfma_f32_16x16x32_bf16(qf[0], k0, s, 0, 0, 0);
      s = __builtin_amdgcn_mfma_f32_16x16x32_bf16(qf[1], k1, s, 0, 0, 0);
      S[c] = s;
    }

    // ---- softmax (C-layout: col = lm, row = 4*lg+reg) ----
    const int s0 = kt * 64;
    const bool diag = (kt == qt);
    float alpha[4];
#pragma unroll
    for (int r = 0; r < 4; ++r) {
      const int rg = q0 + wave * 16 + lg * 4 + r;
      float mx = -1e30f;
#pragma unroll
      for (int c = 0; c < 4; ++c) {
        float v = S[c][r] * SCALEF;
        if (diag && (s0 + c * 16 + lm) > rg) v = -1e30f;
        S[c][r] = v;
        mx = fmaxf(mx, v);
      }
#pragma unroll
      for (int msk = 1; msk < 16; msk <<= 1) mx = fmaxf(mx, __shfl_xor(mx, msk));
      float mnew = fmaxf(m_run[r], mx);
      alpha[r] = __expf(m_run[r] - mnew);
      m_run[r] = mnew;
      float sum = 0.f;
#pragma unroll
      for (int c = 0; c < 4; ++c) {
        float p = __expf(S[c][r] - mnew);
        S[c][r] = p;
        sum += p;
      }
#pragma unroll
      for (int msk = 1; msk < 16; msk <<= 1) sum += __shfl_xor(sum, msk);
      l_run[r] = l_run[r] * alpha[r] + sum;
    }

    // ---- P: C-layout -> LDS (wave-private rows; no barrier needed) ----
#pragma unroll
    for (int r = 0; r < 4; ++r)
#pragma unroll
      for (int c = 0; c < 4; ++c)
        Ps[wave * 16 + lg * 4 + r][c * 16 + lm] = f2bf(S[c][r]);

    // ---- O = O*alpha + P V ----
    bf16x8 pf0 = *(const bf16x8*)&Ps[wave * 16 + lm][kg8];
    bf16x8 pf1 = *(const bf16x8*)&Ps[wave * 16 + lm][32 + kg8];
#pragma unroll
    for (int c = 0; c < 4; ++c) {
      bf16x8 v0 = *(const bf16x8*)&Vt[c * 16 + lm][kg8];
      bf16x8 v1 = *(const bf16x8*)&Vt[c * 16 + lm][32 + kg8];
      f32x4 o = Oa[c];
#pragma unroll
      for (int i = 0; i < 4; ++i) o[i] *= alpha[i];
      o = __builtin_amdgcn_mfma_f32_16x16x32_bf16(pf0, v0, o, 0, 0, 0);
      o = __builtin_amdgcn_mfma_f32_16x16x32_bf16(pf1, v1, o, 0, 0, 0);
      Oa[c] = o;
    }
  }

  // ---- epilogue: O / l -> yb ----
  float inv[4];
#pragma unroll
  for (int r = 0; r < 4; ++r) inv[r] = 1.f / l_run[r];
#pragma unroll
  for (int c = 0; c < 4; ++c) {
    const int col = h * Dz + c * 16 + lm;
#pragma unroll
    for (int r = 0; r < 4; ++r) {
      const int rg = q0 + wave * 16 + lg * 4 + r;
      yb[(size_t)(b * Tz + rg) * Cz + col] = f2bf(Oa[c][r] * inv[r]);
    }
  }
}

extern "C" void kernel_launch(void* const* d_in, const int* in_sizes, int n_in,
                              void* d_out, int out_size, void* d_ws, size_t ws_size,
                              hipStream_t stream) {
  const float* x      = (const float*)d_in[0];
  const float* w_attn = (const float*)d_in[1];
  const float* b_attn = (const float*)d_in[2];
  const float* w_proj = (const float*)d_in[3];
  const float* b_proj = (const float*)d_in[4];

  char* ws = (char*)d_ws;
  u16* xb   = (u16*)(ws);                        //  8 MB: x bf16 [4096,1024]
  u16* waT  = (u16*)(ws + (8ull << 20));         //  6 MB: w_attn^T bf16 [3072,1024]
  u16* wpT  = (u16*)(ws + (14ull << 20));        //  2 MB: w_proj^T bf16 [1024,1024]
  u16* qkvb = (u16*)(ws + (16ull << 20));        // 24 MB: qkv bf16 [4096,3072]
  u16* yb   = (u16*)(ws + (40ull << 20));        //  8 MB: y bf16 [4096,1024]

  const int M = Bz * Tz;  // 4096

  int n4 = (M * Cz) / 4;
  cast_kernel<<<n4 / 256, 256, 0, stream>>>(x, xb, n4);
  transpose_cast_kernel<<<dim3(3 * Cz / 32, Cz / 32), dim3(32, 8), 0, stream>>>(
      w_attn, waT, Cz, 3 * Cz);
  transpose_cast_kernel<<<dim3(Cz / 32, Cz / 32), dim3(32, 8), 0, stream>>>(
      w_proj, wpT, Cz, Cz);
  gemm_bt<true><<<dim3(3 * Cz / 64, M / 64), 256, 0, stream>>>(
      xb, waT, b_attn, qkvb, M, 3 * Cz, Cz);
  attn_kernel<<<dim3(Tz / 64, Bz * Hz), 256, 0, stream>>>(qkvb, yb);
  gemm_bt<false><<<dim3(Cz / 64, M / 64), 256, 0, stream>>>(
      yb, wpT, b_proj, d_out, M, Cz, Cz);
}

// Round 3
// 277.666 us; speedup vs baseline: 2.9177x; 1.0498x over previous
//
#include <hip/hip_runtime.h>

// Causal self-attention fwd: B=2,T=2048,C=1024,H=16,D=64, scale=0.1/sqrt(D)
// cast x->bf16; transpose+cast weights; qkv GEMM (m97-style 128x128 tile,
// global_load_lds w=16, XOR-swizzled LDS); flash attn (MFMA, Q-tile 128,
// register-prefetched K/V); proj GEMM.

#define Bz 2
#define Tz 2048
#define Cz 1024
#define Hz 16
#define Dz 64
#define SCALEF 0.0125f

typedef unsigned short u16;
typedef short bf16x8 __attribute__((ext_vector_type(8)));
typedef float f32x4 __attribute__((ext_vector_type(4)));

__device__ inline u16 f2bf(float f) {
  unsigned u = __float_as_uint(f);
  u += 0x7fffu + ((u >> 16) & 1u);   // round-to-nearest-even
  return (u16)(u >> 16);
}

__device__ inline void gl_lds16(const u16* g, u16* l) {
  __builtin_amdgcn_global_load_lds(
      (const __attribute__((address_space(1))) void*)g,
      (__attribute__((address_space(3))) void*)l, 16, 0, 0);
}

// ---------------- cast fp32 -> bf16, float4-vectorized ----------------
__global__ void cast_kernel(const float* __restrict__ in, u16* __restrict__ out, int n4) {
  int i = blockIdx.x * blockDim.x + threadIdx.x;
  if (i >= n4) return;
  float4 v = ((const float4*)in)[i];
  ushort4 o = {f2bf(v.x), f2bf(v.y), f2bf(v.z), f2bf(v.w)};
  ((ushort4*)out)[i] = o;
}

// ---------- W[K][N] fp32 -> WT[N][K] bf16 (tiled transpose) ----------
__global__ void transpose_cast_kernel(const float* __restrict__ W, u16* __restrict__ WT,
                                      int K, int N) {
  __shared__ float tile[32][33];
  int n0 = blockIdx.x * 32, k0 = blockIdx.y * 32;
  int tx = threadIdx.x, ty = threadIdx.y;  // (32, 8)
#pragma unroll
  for (int i = 0; i < 4; ++i)
    tile[ty + 8 * i][tx] = W[(size_t)(k0 + ty + 8 * i) * N + n0 + tx];
  __syncthreads();
#pragma unroll
  for (int i = 0; i < 4; ++i)
    WT[(size_t)(n0 + ty + 8 * i) * K + k0 + tx] = f2bf(tile[tx][ty + 8 * i]);
}

// ---------- C[M][N] = A[M][K]*BT[N][K]^T + bias, 128x128 tile ----------
// 256 thr = 4 waves (2x2). BK=32. LDS unpadded (global_load_lds order), with
// XOR col-seg swizzle: LDS seg s of row r holds global seg s ^ ((r>>1)&3)
// -> ds_read_b128 frag reads are 2 lanes/bank (free).
template <bool OUT_BF16>
__global__ __launch_bounds__(256) void gemm_bt(const u16* __restrict__ A,
                                               const u16* __restrict__ BT,
                                               const float* __restrict__ bias,
                                               void* __restrict__ Cout,
                                               int M, int N, int K) {
  __shared__ __align__(16) u16 As[128 * 32];
  __shared__ __align__(16) u16 Bs[128 * 32];
  const int t = threadIdx.x;
  const int wave = t >> 6, lane = t & 63;
  const int lm = lane & 15, lg = lane >> 4;
  const int wm = wave >> 1, wn = wave & 1;
  const int m0 = blockIdx.y * 128, n0 = blockIdx.x * 128;

  // staging: wave stages rows [32w+16j, +16), lane i -> row +(i>>2), seg swizzled
  const int srow_in = lane >> 2;                       // 0..15
  const int gseg = (lane & 3) ^ ((lane >> 3) & 3);     // global col-seg for this lane
  const size_t a_off0 = (size_t)(m0 + 32 * wave + srow_in) * K + gseg * 8;
  const size_t a_off1 = a_off0 + 16 * (size_t)K;
  const size_t b_off0 = (size_t)(n0 + 32 * wave + srow_in) * K + gseg * 8;
  const size_t b_off1 = b_off0 + 16 * (size_t)K;
  u16* asl0 = &As[(32 * wave) * 32];
  u16* asl1 = &As[(32 * wave + 16) * 32];
  u16* bsl0 = &Bs[(32 * wave) * 32];
  u16* bsl1 = &Bs[(32 * wave + 16) * 32];

  const int rseg = (lg ^ ((lm >> 1) & 3)) * 8;  // frag-read swizzled seg offset

  f32x4 acc[4][4];
#pragma unroll
  for (int mt = 0; mt < 4; ++mt)
#pragma unroll
    for (int nt = 0; nt < 4; ++nt)
#pragma unroll
      for (int i = 0; i < 4; ++i) acc[mt][nt][i] = 0.f;

  for (int k0 = 0; k0 < K; k0 += 32) {
    __syncthreads();
    gl_lds16(A + a_off0 + k0, asl0);
    gl_lds16(A + a_off1 + k0, asl1);
    gl_lds16(BT + b_off0 + k0, bsl0);
    gl_lds16(BT + b_off1 + k0, bsl1);
    __syncthreads();

    bf16x8 af[4], bfr[4];
#pragma unroll
    for (int mt = 0; mt < 4; ++mt)
      af[mt] = *(const bf16x8*)&As[(64 * wm + 16 * mt + lm) * 32 + rseg];
#pragma unroll
    for (int nt = 0; nt < 4; ++nt)
      bfr[nt] = *(const bf16x8*)&Bs[(64 * wn + 16 * nt + lm) * 32 + rseg];
#pragma unroll
    for (int mt = 0; mt < 4; ++mt)
#pragma unroll
      for (int nt = 0; nt < 4; ++nt)
        acc[mt][nt] = __builtin_amdgcn_mfma_f32_16x16x32_bf16(af[mt], bfr[nt],
                                                              acc[mt][nt], 0, 0, 0);
  }

#pragma unroll
  for (int nt = 0; nt < 4; ++nt) {
    int gc = n0 + 64 * wn + 16 * nt + lm;
    float bv = bias[gc];
#pragma unroll
    for (int mt = 0; mt < 4; ++mt) {
#pragma unroll
      for (int i = 0; i < 4; ++i) {
        int gr = m0 + 64 * wm + 16 * mt + 4 * lg + i;
        float v = acc[mt][nt][i] + bv;
        if (OUT_BF16)
          ((u16*)Cout)[(size_t)gr * N + gc] = f2bf(v);
        else
          ((float*)Cout)[(size_t)gr * N + gc] = v;
      }
    }
  }
}

// ---------------- flash attention, MFMA bf16, Q-tile 128 ----------------
// Grid: (16 qtiles swizzled, B*H). 4 waves; wave w owns rows {16w, 64+16w}
// (rt=0,1). K-tile 64. Next K/V tile register-prefetched right after the
// consume barrier so global latency hides behind QK/softmax/PV.
__global__ __launch_bounds__(256) void attn_kernel(const u16* __restrict__ qkv,
                                                   u16* __restrict__ yb) {
  __shared__ __align__(16) u16 Ks[64][72];
  __shared__ __align__(16) u16 Vt[64][72];
  __shared__ __align__(16) u16 Ps[128][72];

  const int t = threadIdx.x;
  const int wave = t >> 6, lane = t & 63;
  const int lm = lane & 15, lg = lane >> 4;
  const int kg8 = lg << 3;
  const int bx = blockIdx.x;
  const int qt = (bx & 1) ? (15 - (bx >> 1)) : (bx >> 1);  // pair long+short
  const int bh = blockIdx.y;
  const int b = bh >> 4, h = bh & 15;
  const int q0 = qt * 128;
  const size_t rowstride = 3 * Cz;
  const u16* qbase = qkv + (size_t)b * Tz * rowstride + h * Dz;

  // Q fragments (A-layout): rt half, row q0+64*rt+16*wave+lm
  bf16x8 qf[2][2];
#pragma unroll
  for (int rt = 0; rt < 2; ++rt) {
    const u16* qrow = qbase + (size_t)(q0 + 64 * rt + 16 * wave + lm) * rowstride + kg8;
    qf[rt][0] = *(const bf16x8*)qrow;
    qf[rt][1] = *(const bf16x8*)(qrow + 32);
  }

  float m_run[2][4], l_run[2][4];
  f32x4 Oa[2][4];
#pragma unroll
  for (int rt = 0; rt < 2; ++rt)
#pragma unroll
    for (int i = 0; i < 4; ++i) {
      m_run[rt][i] = -1e30f;
      l_run[rt][i] = 0.f;
#pragma unroll
      for (int j = 0; j < 4; ++j) Oa[rt][i][j] = 0.f;
    }

  // staging indices
  const int ksr = t >> 2, kds = (t & 3) << 4;   // K: row, 16-col seg
  const int vsp = t & 31, vds = (t >> 5) << 3;  // V: s-pair, 8-d seg
  const u16* kptr = qbase + Cz + (size_t)ksr * rowstride + kds;
  const u16* vptr = qbase + 2 * Cz + (size_t)(2 * vsp) * rowstride + vds;
  const size_t tilestep = 64 * rowstride;

  const int ktmax = 2 * qt + 1;
  uint4 kreg[2], vreg[2];
  kreg[0] = *(const uint4*)kptr;
  kreg[1] = *(const uint4*)(kptr + 8);
  vreg[0] = *(const uint4*)vptr;
  vreg[1] = *(const uint4*)(vptr + rowstride);

  for (int kt = 0; kt <= ktmax; ++kt) {
    __syncthreads();  // prior tile's Ks/Vt reads complete
    *(uint4*)&Ks[ksr][kds] = kreg[0];
    *(uint4*)&Ks[ksr][kds + 8] = kreg[1];
    {
      unsigned av[4] = {vreg[0].x, vreg[0].y, vreg[0].z, vreg[0].w};
      unsigned cv[4] = {vreg[1].x, vreg[1].y, vreg[1].z, vreg[1].w};
#pragma unroll
      for (int j = 0; j < 4; ++j) {
        unsigned w0 = (av[j] & 0xffffu) | (cv[j] << 16);
        unsigned w1 = (av[j] >> 16) | (cv[j] & 0xffff0000u);
        *(unsigned*)&Vt[vds + 2 * j][2 * vsp] = w0;
        *(unsigned*)&Vt[vds + 2 * j + 1][2 * vsp] = w1;
      }
    }
    __syncthreads();

    // prefetch next tile into registers (overlaps compute below)
    kptr += tilestep;
    vptr += tilestep;
    if (kt < ktmax) {
      kreg[0] = *(const uint4*)kptr;
      kreg[1] = *(const uint4*)(kptr + 8);
      vreg[0] = *(const uint4*)vptr;
      vreg[1] = *(const uint4*)(vptr + rowstride);
    }

    const int s0 = kt * 64;
#pragma unroll
    for (int rt = 0; rt < 2; ++rt) {
      const int rb = q0 + 64 * rt;
      if (s0 > rb) continue;          // fully masked half (only rt=0, kt=ktmax)
      const bool diag = (s0 == rb);

      // ---- S = Q K^T ----
      f32x4 S[4];
#pragma unroll
      for (int c = 0; c < 4; ++c) {
        bf16x8 k0 = *(const bf16x8*)&Ks[c * 16 + lm][kg8];
        bf16x8 k1 = *(const bf16x8*)&Ks[c * 16 + lm][32 + kg8];
        f32x4 s;
#pragma unroll
        for (int i = 0; i < 4; ++i) s[i] = 0.f;
        s = __builtin_amdgcn_mfma_f32_16x16x32_bf16(qf[rt][0], k0, s, 0, 0, 0);
        s = __builtin_amdgcn_mfma_f32_16x16x32_bf16(qf[rt][1], k1, s, 0, 0, 0);
        S[c] = s;
      }

      // ---- softmax (C-layout: col=lm, row=4*lg+r within 16-row tile) ----
      float alpha[4];
#pragma unroll
      for (int r = 0; r < 4; ++r) {
        const int rloc = 16 * wave + lg * 4 + r;  // row within 64-row half
        float mx = -1e30f;
#pragma unroll
        for (int c = 0; c < 4; ++c) {
          float v = S[c][r] * SCALEF;
          if (diag && (c * 16 + lm) > rloc) v = -1e30f;
          S[c][r] = v;
          mx = fmaxf(mx, v);
        }
#pragma unroll
        for (int msk = 1; msk < 16; msk <<= 1) mx = fmaxf(mx, __shfl_xor(mx, msk));
        float mnew = fmaxf(m_run[rt][r], mx);
        alpha[r] = __expf(m_run[rt][r] - mnew);
        m_run[rt][r] = mnew;
        float sum = 0.f;
#pragma unroll
        for (int c = 0; c < 4; ++c) {
          float p = __expf(S[c][r] - mnew);
          S[c][r] = p;
          sum += p;
        }
#pragma unroll
        for (int msk = 1; msk < 16; msk <<= 1) sum += __shfl_xor(sum, msk);
        l_run[rt][r] = l_run[rt][r] * alpha[r] + sum;
      }

      // ---- P: C-layout -> LDS (wave-private rows; no barrier) ----
#pragma unroll
      for (int r = 0; r < 4; ++r)
#pragma unroll
        for (int c = 0; c < 4; ++c)
          Ps[64 * rt + 16 * wave + lg * 4 + r][c * 16 + lm] = f2bf(S[c][r]);

      // ---- O = O*alpha + P V ----
      bf16x8 pf0 = *(const bf16x8*)&Ps[64 * rt + 16 * wave + lm][kg8];
      bf16x8 pf1 = *(const bf16x8*)&Ps[64 * rt + 16 * wave + lm][32 + kg8];
#pragma unroll
      for (int c = 0; c < 4; ++c) {
        bf16x8 v0 = *(const bf16x8*)&Vt[c * 16 + lm][kg8];
        bf16x8 v1 = *(const bf16x8*)&Vt[c * 16 + lm][32 + kg8];
        f32x4 o = Oa[rt][c];
#pragma unroll
        for (int i = 0; i < 4; ++i) o[i] *= alpha[i];
        o = __builtin_amdgcn_mfma_f32_16x16x32_bf16(pf0, v0, o, 0, 0, 0);
        o = __builtin_amdgcn_mfma_f32_16x16x32_bf16(pf1, v1, o, 0, 0, 0);
        Oa[rt][c] = o;
      }
    }
  }

  // ---- epilogue ----
#pragma unroll
  for (int rt = 0; rt < 2; ++rt) {
    float inv[4];
#pragma unroll
    for (int r = 0; r < 4; ++r) inv[r] = 1.f / l_run[rt][r];
#pragma unroll
    for (int c = 0; c < 4; ++c) {
      const int col = h * Dz + c * 16 + lm;
#pragma unroll
      for (int r = 0; r < 4; ++r) {
        const int rg = q0 + 64 * rt + 16 * wave + lg * 4 + r;
        yb[(size_t)(b * Tz + rg) * Cz + col] = f2bf(Oa[rt][c][r] * inv[r]);
      }
    }
  }
}

extern "C" void kernel_launch(void* const* d_in, const int* in_sizes, int n_in,
                              void* d_out, int out_size, void* d_ws, size_t ws_size,
                              hipStream_t stream) {
  const float* x      = (const float*)d_in[0];
  const float* w_attn = (const float*)d_in[1];
  const float* b_attn = (const float*)d_in[2];
  const float* w_proj = (const float*)d_in[3];
  const float* b_proj = (const float*)d_in[4];

  char* ws = (char*)d_ws;
  u16* xb   = (u16*)(ws);                        //  8 MB: x bf16 [4096,1024]
  u16* waT  = (u16*)(ws + (8ull << 20));         //  6 MB: w_attn^T bf16 [3072,1024]
  u16* wpT  = (u16*)(ws + (14ull << 20));        //  2 MB: w_proj^T bf16 [1024,1024]
  u16* qkvb = (u16*)(ws + (16ull << 20));        // 24 MB: qkv bf16 [4096,3072]
  u16* yb   = (u16*)(ws + (40ull << 20));        //  8 MB: y bf16 [4096,1024]

  const int M = Bz * Tz;  // 4096

  int n4 = (M * Cz) / 4;
  cast_kernel<<<n4 / 256, 256, 0, stream>>>(x, xb, n4);
  transpose_cast_kernel<<<dim3(3 * Cz / 32, Cz / 32), dim3(32, 8), 0, stream>>>(
      w_attn, waT, Cz, 3 * Cz);
  transpose_cast_kernel<<<dim3(Cz / 32, Cz / 32), dim3(32, 8), 0, stream>>>(
      w_proj, wpT, Cz, Cz);
  gemm_bt<true><<<dim3(3 * Cz / 128, M / 128), 256, 0, stream>>>(
      xb, waT, b_attn, qkvb, M, 3 * Cz, Cz);
  attn_kernel<<<dim3(Tz / 128, Bz * Hz), 256, 0, stream>>>(qkvb, yb);
  gemm_bt<false><<<dim3(Cz / 128, M / 128), 256, 0, stream>>>(
      yb, wpT, b_proj, d_out, M, Cz, Cz);
}

// Round 4
// 244.745 us; speedup vs baseline: 3.3102x; 1.1345x over previous
//
#include <hip/hip_runtime.h>

// Causal self-attention fwd: B=2,T=2048,C=1024,H=16,D=64, scale=0.1/sqrt(D)
// prep (cast x + transpose weights, 1 kernel); qkv GEMM 128x128 w/
// global_load_lds + XOR swizzle, q-cols pre-scaled by SCALE*log2e;
// flash attn (MFMA, Q-tile 64, m=0 softmax: no max/no alpha, deferred l);
// proj GEMM 128x64.

#define Bz 2
#define Tz 2048
#define Cz 1024
#define Hz 16
#define Dz 64
// SCALE * log2(e): q pre-scaled so attn does p = exp2(S) directly
#define QSCALE 0.01803368801111437f

typedef unsigned short u16;
typedef short bf16x8 __attribute__((ext_vector_type(8)));
typedef float f32x4 __attribute__((ext_vector_type(4)));

__device__ inline u16 f2bf(float f) {  // round-half-up: 2 VALU, <=0.5 ulp
  return (u16)((__float_as_uint(f) + 0x8000u) >> 16);
}

__device__ inline float fexp2(float x) {
#if __has_builtin(__builtin_amdgcn_exp2f)
  return __builtin_amdgcn_exp2f(x);
#else
  return exp2f(x);
#endif
}

__device__ inline void gl_lds16(const u16* g, u16* l) {
  __builtin_amdgcn_global_load_lds(
      (const __attribute__((address_space(1))) void*)g,
      (__attribute__((address_space(3))) void*)l, 16, 0, 0);
}

// ------------- prep: cast x->bf16 + transpose/cast both weights -------------
#define NCAST 4096   // (4096*1024/4)/256
#define NTA   3072   // (3072/32)*(1024/32)
__global__ __launch_bounds__(256) void prep_kernel(const float* __restrict__ x,
                                                   const float* __restrict__ wa,
                                                   const float* __restrict__ wp,
                                                   u16* __restrict__ xb,
                                                   u16* __restrict__ waT,
                                                   u16* __restrict__ wpT) {
  const int bx = blockIdx.x, t = threadIdx.x;
  if (bx < NCAST) {
    int i = bx * 256 + t;
    float4 v = ((const float4*)x)[i];
    ushort4 o = {f2bf(v.x), f2bf(v.y), f2bf(v.z), f2bf(v.w)};
    ((ushort4*)xb)[i] = o;
    return;
  }
  __shared__ float tile[32][33];
  const float* W;
  u16* WT;
  int N, idx;
  if (bx < NCAST + NTA) {
    W = wa; WT = waT; N = 3 * Cz; idx = bx - NCAST;
  } else {
    W = wp; WT = wpT; N = Cz; idx = bx - NCAST - NTA;
  }
  const int n0 = (idx % (N / 32)) * 32, k0 = (idx / (N / 32)) * 32;
  const int tx = t & 31, ty = t >> 5;  // (32, 8)
#pragma unroll
  for (int i = 0; i < 4; ++i)
    tile[ty + 8 * i][tx] = W[(size_t)(k0 + ty + 8 * i) * N + n0 + tx];
  __syncthreads();
#pragma unroll
  for (int i = 0; i < 4; ++i)
    WT[(size_t)(n0 + ty + 8 * i) * Cz + k0 + tx] = f2bf(tile[tx][ty + 8 * i]);
}

// ---------- C[M][N] = A[M][K]*BT[N][K]^T + bias; 128xTN tile ----------
// cols < qcols get (acc+bias)*qscale (pre-scales q for attn exp2).
template <bool OUT_BF16, int TN>
__global__ __launch_bounds__(256) void gemm_bt(const u16* __restrict__ A,
                                               const u16* __restrict__ BT,
                                               const float* __restrict__ bias,
                                               void* __restrict__ Cout,
                                               int M, int N, int K,
                                               int qcols, float qscale) {
  __shared__ __align__(16) u16 As[128 * 32];
  __shared__ __align__(16) u16 Bs[TN * 32];
  constexpr int NT = TN / 32;
  const int t = threadIdx.x;
  const int wave = t >> 6, lane = t & 63;
  const int lm = lane & 15, lg = lane >> 4;
  const int wm = wave >> 1, wn = wave & 1;
  const int m0 = blockIdx.y * 128, n0 = blockIdx.x * TN;

  const int srow_in = lane >> 2;
  const int gseg = (lane & 3) ^ ((lane >> 3) & 3);  // XOR col-seg swizzle
  const size_t a_off0 = (size_t)(m0 + 32 * wave + srow_in) * K + gseg * 8;
  const size_t a_off1 = a_off0 + 16 * (size_t)K;
  u16* asl0 = &As[(32 * wave) * 32];
  u16* asl1 = &As[(32 * wave + 16) * 32];
  size_t b_off0 = 0, b_off1 = 0;
  u16 *bsl0, *bsl1 = nullptr;
  if constexpr (TN == 128) {
    b_off0 = (size_t)(n0 + 32 * wave + srow_in) * K + gseg * 8;
    b_off1 = b_off0 + 16 * (size_t)K;
    bsl0 = &Bs[(32 * wave) * 32];
    bsl1 = &Bs[(32 * wave + 16) * 32];
  } else {
    b_off0 = (size_t)(n0 + 16 * wave + srow_in) * K + gseg * 8;
    bsl0 = &Bs[(16 * wave) * 32];
  }
  const int rseg = (lg ^ ((lm >> 1) & 3)) * 8;

  f32x4 acc[4][NT];
#pragma unroll
  for (int mt = 0; mt < 4; ++mt)
#pragma unroll
    for (int nt = 0; nt < NT; ++nt)
#pragma unroll
      for (int i = 0; i < 4; ++i) acc[mt][nt][i] = 0.f;

  for (int k0 = 0; k0 < K; k0 += 32) {
    __syncthreads();
    gl_lds16(A + a_off0 + k0, asl0);
    gl_lds16(A + a_off1 + k0, asl1);
    gl_lds16(BT + b_off0 + k0, bsl0);
    if constexpr (TN == 128) gl_lds16(BT + b_off1 + k0, bsl1);
    __syncthreads();

    bf16x8 af[4], bfr[NT];
#pragma unroll
    for (int mt = 0; mt < 4; ++mt)
      af[mt] = *(const bf16x8*)&As[(64 * wm + 16 * mt + lm) * 32 + rseg];
#pragma unroll
    for (int nt = 0; nt < NT; ++nt)
      bfr[nt] = *(const bf16x8*)&Bs[((TN / 2) * wn + 16 * nt + lm) * 32 + rseg];
#pragma unroll
    for (int mt = 0; mt < 4; ++mt)
#pragma unroll
      for (int nt = 0; nt < NT; ++nt)
        acc[mt][nt] = __builtin_amdgcn_mfma_f32_16x16x32_bf16(af[mt], bfr[nt],
                                                              acc[mt][nt], 0, 0, 0);
  }

#pragma unroll
  for (int nt = 0; nt < NT; ++nt) {
    int gc = n0 + (TN / 2) * wn + 16 * nt + lm;
    float bv = bias[gc];
    float sc = (gc < qcols) ? qscale : 1.f;
#pragma unroll
    for (int mt = 0; mt < 4; ++mt) {
#pragma unroll
      for (int i = 0; i < 4; ++i) {
        int gr = m0 + 64 * wm + 16 * mt + 4 * lg + i;
        float v = (acc[mt][nt][i] + bv) * sc;
        if (OUT_BF16)
          ((u16*)Cout)[(size_t)gr * N + gc] = f2bf(v);
        else
          ((float*)Cout)[(size_t)gr * N + gc] = v;
      }
    }
  }
}

// ---------------- flash attention, MFMA bf16, m=0 softmax ----------------
// Grid: (32 qtiles pair-swizzled, B*H). 4 waves; wave w owns Q-rows
// [64qt+16w, +16). q pre-scaled by SCALE*log2e -> p = exp2(S), masked by
// cndmask; l deferred to one 16-lane butterfly in epilogue. K/V register
// prefetch hides global latency behind compute.
__global__ __launch_bounds__(256) void attn_kernel(const u16* __restrict__ qkv,
                                                   u16* __restrict__ yb) {
  __shared__ __align__(16) u16 Ks[64][72];
  __shared__ __align__(16) u16 Vt[64][72];
  __shared__ __align__(16) u16 Ps[64][72];

  const int t = threadIdx.x;
  const int wave = t >> 6, lane = t & 63;
  const int lm = lane & 15, lg = lane >> 4;
  const int kg8 = lg << 3;
  const int bx = blockIdx.x;
  const int qt = (bx & 1) ? (31 - (bx >> 1)) : (bx >> 1);  // pair long+short
  const int bh = blockIdx.y;
  const int b = bh >> 4, h = bh & 15;
  const int q0 = qt * 64;
  const size_t rowstride = 3 * Cz;
  const u16* qbase = qkv + (size_t)b * Tz * rowstride + h * Dz;

  bf16x8 qf[2];
  {
    const u16* qrow = qbase + (size_t)(q0 + wave * 16 + lm) * rowstride + kg8;
    qf[0] = *(const bf16x8*)qrow;
    qf[1] = *(const bf16x8*)(qrow + 32);
  }

  float psum[4];
  f32x4 Oa[4];
#pragma unroll
  for (int i = 0; i < 4; ++i) {
    psum[i] = 0.f;
#pragma unroll
    for (int j = 0; j < 4; ++j) Oa[i][j] = 0.f;
  }

  const int ksr = t >> 2, kds = (t & 3) << 4;
  const int vsp = t & 31, vds = (t >> 5) << 3;
  const u16* kptr = qbase + Cz + (size_t)ksr * rowstride + kds;
  const u16* vptr = qbase + 2 * Cz + (size_t)(2 * vsp) * rowstride + vds;
  const size_t tilestep = 64 * rowstride;

  uint4 kreg[2], vreg[2];
  kreg[0] = *(const uint4*)kptr;
  kreg[1] = *(const uint4*)(kptr + 8);
  vreg[0] = *(const uint4*)vptr;
  vreg[1] = *(const uint4*)(vptr + rowstride);

  for (int kt = 0; kt <= qt; ++kt) {
    __syncthreads();
    *(uint4*)&Ks[ksr][kds] = kreg[0];
    *(uint4*)&Ks[ksr][kds + 8] = kreg[1];
    {
      unsigned av[4] = {vreg[0].x, vreg[0].y, vreg[0].z, vreg[0].w};
      unsigned cv[4] = {vreg[1].x, vreg[1].y, vreg[1].z, vreg[1].w};
#pragma unroll
      for (int j = 0; j < 4; ++j) {
        unsigned w0 = (av[j] & 0xffffu) | (cv[j] << 16);
        unsigned w1 = (av[j] >> 16) | (cv[j] & 0xffff0000u);
        *(unsigned*)&Vt[vds + 2 * j][2 * vsp] = w0;
        *(unsigned*)&Vt[vds + 2 * j + 1][2 * vsp] = w1;
      }
    }
    __syncthreads();

    // prefetch next tile (overlaps compute)
    kptr += tilestep;
    vptr += tilestep;
    if (kt < qt) {
      kreg[0] = *(const uint4*)kptr;
      kreg[1] = *(const uint4*)(kptr + 8);
      vreg[0] = *(const uint4*)vptr;
      vreg[1] = *(const uint4*)(vptr + rowstride);
    }

    // ---- S = Q K^T (pre-scaled) ----
    f32x4 S[4];
#pragma unroll
    for (int c = 0; c < 4; ++c) {
      bf16x8 k0 = *(const bf16x8*)&Ks[c * 16 + lm][kg8];
      bf16x8 k1 = *(const bf16x8*)&Ks[c * 16 + lm][32 + kg8];
      f32x4 s;
#pragma unroll
      for (int i = 0; i < 4; ++i) s[i] = 0.f;
      s = __builtin_amdgcn_mfma_f32_16x16x32_bf16(qf[0], k0, s, 0, 0, 0);
      s = __builtin_amdgcn_mfma_f32_16x16x32_bf16(qf[1], k1, s, 0, 0, 0);
      S[c] = s;
    }

    // ---- p = exp2(S), mask on diag, accumulate l, write P ----
    const bool diag = (kt == qt);
#pragma unroll
    for (int c = 0; c < 4; ++c) {
#pragma unroll
      for (int r = 0; r < 4; ++r) {
        float p = fexp2(S[c][r]);
        if (diag && (c * 16 + lm) > (16 * wave + 4 * lg + r)) p = 0.f;
        psum[r] += p;
        Ps[16 * wave + 4 * lg + r][c * 16 + lm] = f2bf(p);
      }
    }

    // ---- O += P V (no rescale) ----
    bf16x8 pf0 = *(const bf16x8*)&Ps[16 * wave + lm][kg8];
    bf16x8 pf1 = *(const bf16x8*)&Ps[16 * wave + lm][32 + kg8];
#pragma unroll
    for (int c = 0; c < 4; ++c) {
      bf16x8 v0 = *(const bf16x8*)&Vt[c * 16 + lm][kg8];
      bf16x8 v1 = *(const bf16x8*)&Vt[c * 16 + lm][32 + kg8];
      Oa[c] = __builtin_amdgcn_mfma_f32_16x16x32_bf16(pf0, v0, Oa[c], 0, 0, 0);
      Oa[c] = __builtin_amdgcn_mfma_f32_16x16x32_bf16(pf1, v1, Oa[c], 0, 0, 0);
    }
  }

  // ---- epilogue: one l-reduction, normalize, store ----
  float inv[4];
#pragma unroll
  for (int r = 0; r < 4; ++r) {
    float s = psum[r];
#pragma unroll
    for (int msk = 1; msk < 16; msk <<= 1) s += __shfl_xor(s, msk);
    inv[r] = 1.f / s;
  }
#pragma unroll
  for (int c = 0; c < 4; ++c) {
    const int col = h * Dz + c * 16 + lm;
#pragma unroll
    for (int r = 0; r < 4; ++r) {
      const int rg = q0 + 16 * wave + 4 * lg + r;
      yb[(size_t)(b * Tz + rg) * Cz + col] = f2bf(Oa[c][r] * inv[r]);
    }
  }
}

extern "C" void kernel_launch(void* const* d_in, const int* in_sizes, int n_in,
                              void* d_out, int out_size, void* d_ws, size_t ws_size,
                              hipStream_t stream) {
  const float* x      = (const float*)d_in[0];
  const float* w_attn = (const float*)d_in[1];
  const float* b_attn = (const float*)d_in[2];
  const float* w_proj = (const float*)d_in[3];
  const float* b_proj = (const float*)d_in[4];

  char* ws = (char*)d_ws;
  u16* xb   = (u16*)(ws);                        //  8 MB: x bf16 [4096,1024]
  u16* waT  = (u16*)(ws + (8ull << 20));         //  6 MB: w_attn^T bf16 [3072,1024]
  u16* wpT  = (u16*)(ws + (14ull << 20));        //  2 MB: w_proj^T bf16 [1024,1024]
  u16* qkvb = (u16*)(ws + (16ull << 20));        // 24 MB: qkv bf16 (q pre-scaled)
  u16* yb   = (u16*)(ws + (40ull << 20));        //  8 MB: y bf16 [4096,1024]

  const int M = Bz * Tz;  // 4096

  prep_kernel<<<NCAST + NTA + 1024, 256, 0, stream>>>(x, w_attn, w_proj, xb, waT, wpT);
  gemm_bt<true, 128><<<dim3(3 * Cz / 128, M / 128), 256, 0, stream>>>(
      xb, waT, b_attn, qkvb, M, 3 * Cz, Cz, Cz, QSCALE);
  attn_kernel<<<dim3(Tz / 64, Bz * Hz), 256, 0, stream>>>(qkvb, yb);
  gemm_bt<false, 64><<<dim3(Cz / 64, M / 128), 256, 0, stream>>>(
      yb, wpT, b_proj, d_out, M, Cz, Cz, 0, 1.f);
}

// Round 5
// 231.455 us; speedup vs baseline: 3.5003x; 1.0574x over previous
//
#include <hip/hip_runtime.h>

// Causal self-attention fwd: B=2,T=2048,C=1024,H=16,D=64, scale=0.1/sqrt(D)
// prep (cast x + transpose weights); qkv GEMM 128x128 w/ global_load_lds +
// XOR swizzle, q-cols pre-scaled by SCALE*log2e; flash attn (MFMA, m=0
// softmax, 2-deep register prefetch pipeline, XCD-affine grid, coalesced
// epilogue); proj GEMM 128x64.

#define Bz 2
#define Tz 2048
#define Cz 1024
#define Hz 16
#define Dz 64
// SCALE * log2(e): q pre-scaled so attn does p = exp2(S) directly
#define QSCALE 0.01803368801111437f

typedef unsigned short u16;
typedef short bf16x8 __attribute__((ext_vector_type(8)));
typedef float f32x4 __attribute__((ext_vector_type(4)));

__device__ inline u16 f2bf(float f) {  // round-half-up: 2 VALU, <=0.5 ulp
  return (u16)((__float_as_uint(f) + 0x8000u) >> 16);
}

__device__ inline float fexp2(float x) {
#if __has_builtin(__builtin_amdgcn_exp2f)
  return __builtin_amdgcn_exp2f(x);
#else
  return exp2f(x);
#endif
}

__device__ inline void gl_lds16(const u16* g, u16* l) {
  __builtin_amdgcn_global_load_lds(
      (const __attribute__((address_space(1))) void*)g,
      (__attribute__((address_space(3))) void*)l, 16, 0, 0);
}

// ------------- prep: cast x->bf16 + transpose/cast both weights -------------
#define NCAST 4096   // (4096*1024/4)/256
#define NTA   3072   // (3072/32)*(1024/32)
__global__ __launch_bounds__(256) void prep_kernel(const float* __restrict__ x,
                                                   const float* __restrict__ wa,
                                                   const float* __restrict__ wp,
                                                   u16* __restrict__ xb,
                                                   u16* __restrict__ waT,
                                                   u16* __restrict__ wpT) {
  const int bx = blockIdx.x, t = threadIdx.x;
  if (bx < NCAST) {
    int i = bx * 256 + t;
    float4 v = ((const float4*)x)[i];
    ushort4 o = {f2bf(v.x), f2bf(v.y), f2bf(v.z), f2bf(v.w)};
    ((ushort4*)xb)[i] = o;
    return;
  }
  __shared__ float tile[32][33];
  const float* W;
  u16* WT;
  int N, idx;
  if (bx < NCAST + NTA) {
    W = wa; WT = waT; N = 3 * Cz; idx = bx - NCAST;
  } else {
    W = wp; WT = wpT; N = Cz; idx = bx - NCAST - NTA;
  }
  const int n0 = (idx % (N / 32)) * 32, k0 = (idx / (N / 32)) * 32;
  const int tx = t & 31, ty = t >> 5;  // (32, 8)
#pragma unroll
  for (int i = 0; i < 4; ++i)
    tile[ty + 8 * i][tx] = W[(size_t)(k0 + ty + 8 * i) * N + n0 + tx];
  __syncthreads();
#pragma unroll
  for (int i = 0; i < 4; ++i)
    WT[(size_t)(n0 + ty + 8 * i) * Cz + k0 + tx] = f2bf(tile[tx][ty + 8 * i]);
}

// ---------- C[M][N] = A[M][K]*BT[N][K]^T + bias; 128xTN tile ----------
// cols < qcols get (acc+bias)*qscale (pre-scales q for attn exp2).
template <bool OUT_BF16, int TN>
__global__ __launch_bounds__(256) void gemm_bt(const u16* __restrict__ A,
                                               const u16* __restrict__ BT,
                                               const float* __restrict__ bias,
                                               void* __restrict__ Cout,
                                               int M, int N, int K,
                                               int qcols, float qscale) {
  __shared__ __align__(16) u16 As[128 * 32];
  __shared__ __align__(16) u16 Bs[TN * 32];
  constexpr int NT = TN / 32;
  const int t = threadIdx.x;
  const int wave = t >> 6, lane = t & 63;
  const int lm = lane & 15, lg = lane >> 4;
  const int wm = wave >> 1, wn = wave & 1;
  const int m0 = blockIdx.y * 128, n0 = blockIdx.x * TN;

  const int srow_in = lane >> 2;
  const int gseg = (lane & 3) ^ ((lane >> 3) & 3);  // XOR col-seg swizzle
  const size_t a_off0 = (size_t)(m0 + 32 * wave + srow_in) * K + gseg * 8;
  const size_t a_off1 = a_off0 + 16 * (size_t)K;
  u16* asl0 = &As[(32 * wave) * 32];
  u16* asl1 = &As[(32 * wave + 16) * 32];
  size_t b_off0 = 0, b_off1 = 0;
  u16 *bsl0, *bsl1 = nullptr;
  if constexpr (TN == 128) {
    b_off0 = (size_t)(n0 + 32 * wave + srow_in) * K + gseg * 8;
    b_off1 = b_off0 + 16 * (size_t)K;
    bsl0 = &Bs[(32 * wave) * 32];
    bsl1 = &Bs[(32 * wave + 16) * 32];
  } else {
    b_off0 = (size_t)(n0 + 16 * wave + srow_in) * K + gseg * 8;
    bsl0 = &Bs[(16 * wave) * 32];
  }
  const int rseg = (lg ^ ((lm >> 1) & 3)) * 8;

  f32x4 acc[4][NT];
#pragma unroll
  for (int mt = 0; mt < 4; ++mt)
#pragma unroll
    for (int nt = 0; nt < NT; ++nt)
#pragma unroll
      for (int i = 0; i < 4; ++i) acc[mt][nt][i] = 0.f;

  for (int k0 = 0; k0 < K; k0 += 32) {
    __syncthreads();
    gl_lds16(A + a_off0 + k0, asl0);
    gl_lds16(A + a_off1 + k0, asl1);
    gl_lds16(BT + b_off0 + k0, bsl0);
    if constexpr (TN == 128) gl_lds16(BT + b_off1 + k0, bsl1);
    __syncthreads();

    bf16x8 af[4], bfr[NT];
#pragma unroll
    for (int mt = 0; mt < 4; ++mt)
      af[mt] = *(const bf16x8*)&As[(64 * wm + 16 * mt + lm) * 32 + rseg];
#pragma unroll
    for (int nt = 0; nt < NT; ++nt)
      bfr[nt] = *(const bf16x8*)&Bs[((TN / 2) * wn + 16 * nt + lm) * 32 + rseg];
#pragma unroll
    for (int mt = 0; mt < 4; ++mt)
#pragma unroll
      for (int nt = 0; nt < NT; ++nt)
        acc[mt][nt] = __builtin_amdgcn_mfma_f32_16x16x32_bf16(af[mt], bfr[nt],
                                                              acc[mt][nt], 0, 0, 0);
  }

#pragma unroll
  for (int nt = 0; nt < NT; ++nt) {
    int gc = n0 + (TN / 2) * wn + 16 * nt + lm;
    float bv = bias[gc];
    float sc = (gc < qcols) ? qscale : 1.f;
#pragma unroll
    for (int mt = 0; mt < 4; ++mt) {
#pragma unroll
      for (int i = 0; i < 4; ++i) {
        int gr = m0 + 64 * wm + 16 * mt + 4 * lg + i;
        float v = (acc[mt][nt][i] + bv) * sc;
        if (OUT_BF16)
          ((u16*)Cout)[(size_t)gr * N + gc] = f2bf(v);
        else
          ((float*)Cout)[(size_t)gr * N + gc] = v;
      }
    }
  }
}

// ---------------- flash attention, MFMA bf16, m=0 softmax ----------------
// 1D grid of 1024: x = qtp*32 + bh -> blockIdx%8 == bh%8 (XCD L2 affinity for
// shared K/V); qt pair-swizzled for causal balance. 4 waves; wave w owns
// Q-rows [64qt+16w,+16). 2-deep register prefetch (tiles kt+2/kt+3 load while
// kt computes). p = exp2(S) (q pre-scaled), l deferred to epilogue butterfly.
// Epilogue bounces O through wave-private Ps rows for 16B coalesced stores.
__global__ __launch_bounds__(256) void attn_kernel(const u16* __restrict__ qkv,
                                                   u16* __restrict__ yb) {
  __shared__ __align__(16) u16 Ks[64][72];
  __shared__ __align__(16) u16 Vt[64][72];
  __shared__ __align__(16) u16 Ps[64][72];

  const int t = threadIdx.x;
  const int wave = t >> 6, lane = t & 63;
  const int lm = lane & 15, lg = lane >> 4;
  const int kg8 = lg << 3;
  const int x = blockIdx.x;
  const int bh = x & 31, qtp = x >> 5;
  const int qt = (qtp & 1) ? (31 - (qtp >> 1)) : (qtp >> 1);  // pair long+short
  const int b = bh >> 4, h = bh & 15;
  const int q0 = qt * 64;
  const size_t rowstride = 3 * Cz;
  const u16* qbase = qkv + (size_t)b * Tz * rowstride + h * Dz;

  bf16x8 qf[2];
  {
    const u16* qrow = qbase + (size_t)(q0 + wave * 16 + lm) * rowstride + kg8;
    qf[0] = *(const bf16x8*)qrow;
    qf[1] = *(const bf16x8*)(qrow + 32);
  }

  float psum[4];
  f32x4 Oa[4];
#pragma unroll
  for (int i = 0; i < 4; ++i) {
    psum[i] = 0.f;
#pragma unroll
    for (int j = 0; j < 4; ++j) Oa[i][j] = 0.f;
  }

  // per-thread staging offsets
  const int ksr = t >> 2, kds = (t & 3) << 4;   // K: row, 16-col seg
  const int vsp = t & 31, vds = (t >> 5) << 3;  // V: s-pair, 8-d seg
  const u16* kbase = qbase + Cz + (size_t)ksr * rowstride + kds;
  const u16* vbase = qbase + 2 * Cz + (size_t)(2 * vsp) * rowstride + vds;
  const size_t tilestep = 64 * rowstride;

  uint4 krA[2], vrA[2], krB[2], vrB[2];
  {  // prologue: prefetch tiles 0 and min(1,qt)
    const u16* kp = kbase;
    const u16* vp = vbase;
    krA[0] = *(const uint4*)kp;
    krA[1] = *(const uint4*)(kp + 8);
    vrA[0] = *(const uint4*)vp;
    vrA[1] = *(const uint4*)(vp + rowstride);
    const int t1 = (qt >= 1) ? 1 : 0;
    kp = kbase + (size_t)t1 * tilestep;
    vp = vbase + (size_t)t1 * tilestep;
    krB[0] = *(const uint4*)kp;
    krB[1] = *(const uint4*)(kp + 8);
    vrB[0] = *(const uint4*)vp;
    vrB[1] = *(const uint4*)(vp + rowstride);
  }

  auto stage = [&](uint4 (&kr)[2], uint4 (&vr)[2], int ktc) {
    __syncthreads();  // prior stage's Ks/Vt reads complete
    *(uint4*)&Ks[ksr][kds] = kr[0];
    *(uint4*)&Ks[ksr][kds + 8] = kr[1];
    {
      unsigned av[4] = {vr[0].x, vr[0].y, vr[0].z, vr[0].w};
      unsigned cv[4] = {vr[1].x, vr[1].y, vr[1].z, vr[1].w};
#pragma unroll
      for (int j = 0; j < 4; ++j) {
        unsigned w0 = (av[j] & 0xffffu) | (cv[j] << 16);
        unsigned w1 = (av[j] >> 16) | (cv[j] & 0xffff0000u);
        *(unsigned*)&Vt[vds + 2 * j][2 * vsp] = w0;
        *(unsigned*)&Vt[vds + 2 * j + 1][2 * vsp] = w1;
      }
    }
    __syncthreads();

    // prefetch tile ktc+2 into this stage's regs (clamped; unused if > qt)
    {
      const int ktn = (ktc + 2 <= qt) ? (ktc + 2) : qt;
      const u16* kp = kbase + (size_t)ktn * tilestep;
      const u16* vp = vbase + (size_t)ktn * tilestep;
      kr[0] = *(const uint4*)kp;
      kr[1] = *(const uint4*)(kp + 8);
      vr[0] = *(const uint4*)vp;
      vr[1] = *(const uint4*)(vp + rowstride);
    }

    // ---- S = Q K^T (pre-scaled) ----
    f32x4 S[4];
#pragma unroll
    for (int c = 0; c < 4; ++c) {
      bf16x8 k0 = *(const bf16x8*)&Ks[c * 16 + lm][kg8];
      bf16x8 k1 = *(const bf16x8*)&Ks[c * 16 + lm][32 + kg8];
      f32x4 s;
#pragma unroll
      for (int i = 0; i < 4; ++i) s[i] = 0.f;
      s = __builtin_amdgcn_mfma_f32_16x16x32_bf16(qf[0], k0, s, 0, 0, 0);
      s = __builtin_amdgcn_mfma_f32_16x16x32_bf16(qf[1], k1, s, 0, 0, 0);
      S[c] = s;
    }

    // ---- p = exp2(S), diag mask, accumulate l, write P ----
    const bool diag = (ktc == qt);
#pragma unroll
    for (int c = 0; c < 4; ++c) {
#pragma unroll
      for (int r = 0; r < 4; ++r) {
        float p = fexp2(S[c][r]);
        if (diag && (c * 16 + lm) > (16 * wave + 4 * lg + r)) p = 0.f;
        psum[r] += p;
        Ps[16 * wave + 4 * lg + r][c * 16 + lm] = f2bf(p);
      }
    }

    // ---- O += P V ----
    bf16x8 pf0 = *(const bf16x8*)&Ps[16 * wave + lm][kg8];
    bf16x8 pf1 = *(const bf16x8*)&Ps[16 * wave + lm][32 + kg8];
#pragma unroll
    for (int c = 0; c < 4; ++c) {
      bf16x8 v0 = *(const bf16x8*)&Vt[c * 16 + lm][kg8];
      bf16x8 v1 = *(const bf16x8*)&Vt[c * 16 + lm][32 + kg8];
      Oa[c] = __builtin_amdgcn_mfma_f32_16x16x32_bf16(pf0, v0, Oa[c], 0, 0, 0);
      Oa[c] = __builtin_amdgcn_mfma_f32_16x16x32_bf16(pf1, v1, Oa[c], 0, 0, 0);
    }
  };

  for (int kt = 0; kt <= qt; kt += 2) {
    stage(krA, vrA, kt);
    if (kt + 1 <= qt) stage(krB, vrB, kt + 1);
  }

  // ---- epilogue: l-reduction, normalize, bounce via Ps, coalesced store ----
  float inv[4];
#pragma unroll
  for (int r = 0; r < 4; ++r) {
    float s = psum[r];
#pragma unroll
    for (int msk = 1; msk < 16; msk <<= 1) s += __shfl_xor(s, msk);
    inv[r] = 1.f / s;
  }
  // Ps rows [16w,16w+16) are wave-private: no barrier needed
#pragma unroll
  for (int c = 0; c < 4; ++c)
#pragma unroll
    for (int r = 0; r < 4; ++r)
      Ps[16 * wave + 4 * lg + r][c * 16 + lm] = f2bf(Oa[c][r] * inv[r]);

  {
    const int row = lane >> 2, seg = lane & 3;
    const uint4* src = (const uint4*)&Ps[16 * wave + row][seg * 16];
    uint4 v0 = src[0];
    uint4 v1 = src[1];
    u16* dst = yb + (size_t)(b * Tz + q0 + 16 * wave + row) * Cz + h * Dz + seg * 16;
    *(uint4*)dst = v0;
    *(uint4*)(dst + 8) = v1;
  }
}

extern "C" void kernel_launch(void* const* d_in, const int* in_sizes, int n_in,
                              void* d_out, int out_size, void* d_ws, size_t ws_size,
                              hipStream_t stream) {
  const float* x      = (const float*)d_in[0];
  const float* w_attn = (const float*)d_in[1];
  const float* b_attn = (const float*)d_in[2];
  const float* w_proj = (const float*)d_in[3];
  const float* b_proj = (const float*)d_in[4];

  char* ws = (char*)d_ws;
  u16* xb   = (u16*)(ws);                        //  8 MB: x bf16 [4096,1024]
  u16* waT  = (u16*)(ws + (8ull << 20));         //  6 MB: w_attn^T bf16 [3072,1024]
  u16* wpT  = (u16*)(ws + (14ull << 20));        //  2 MB: w_proj^T bf16 [1024,1024]
  u16* qkvb = (u16*)(ws + (16ull << 20));        // 24 MB: qkv bf16 (q pre-scaled)
  u16* yb   = (u16*)(ws + (40ull << 20));        //  8 MB: y bf16 [4096,1024]

  const int M = Bz * Tz;  // 4096

  prep_kernel<<<NCAST + NTA + 1024, 256, 0, stream>>>(x, w_attn, w_proj, xb, waT, wpT);
  gemm_bt<true, 128><<<dim3(3 * Cz / 128, M / 128), 256, 0, stream>>>(
      xb, waT, b_attn, qkvb, M, 3 * Cz, Cz, Cz, QSCALE);
  attn_kernel<<<1024, 256, 0, stream>>>(qkvb, yb);
  gemm_bt<false, 64><<<dim3(Cz / 64, M / 128), 256, 0, stream>>>(
      yb, wpT, b_proj, d_out, M, Cz, Cz, 0, 1.f);
}

// Round 6
// 204.977 us; speedup vs baseline: 3.9524x; 1.1292x over previous
//
#include <hip/hip_runtime.h>

// Causal self-attention fwd: B=2,T=2048,C=1024,H=16,D=64, scale=0.1/sqrt(D)
// prep (cast x + transpose weights); qkv GEMM 128x128 w/ global_load_lds +
// XOR swizzle, q-cols pre-scaled by SCALE*log2e; flash attn (MFMA, m=0
// softmax, 2-deep register prefetch pipeline, XCD-affine grid, CU-balanced
// qt map, coalesced epilogue); proj GEMM 128x64.

#define Bz 2
#define Tz 2048
#define Cz 1024
#define Hz 16
#define Dz 64
// SCALE * log2(e): q pre-scaled so attn does p = exp2(S) directly
#define QSCALE 0.01803368801111437f

typedef unsigned short u16;
typedef short bf16x8 __attribute__((ext_vector_type(8)));
typedef float f32x4 __attribute__((ext_vector_type(4)));

__device__ inline u16 f2bf(float f) {  // round-half-up: 2 VALU, <=0.5 ulp
  return (u16)((__float_as_uint(f) + 0x8000u) >> 16);
}

__device__ inline float fexp2(float x) {
#if __has_builtin(__builtin_amdgcn_exp2f)
  return __builtin_amdgcn_exp2f(x);
#else
  return exp2f(x);
#endif
}

__device__ inline void gl_lds16(const u16* g, u16* l) {
  __builtin_amdgcn_global_load_lds(
      (const __attribute__((address_space(1))) void*)g,
      (__attribute__((address_space(3))) void*)l, 16, 0, 0);
}

// ------------- prep: cast x->bf16 + transpose/cast both weights -------------
#define NCAST 4096   // (4096*1024/4)/256
#define NTA   3072   // (3072/32)*(1024/32)
__global__ __launch_bounds__(256) void prep_kernel(const float* __restrict__ x,
                                                   const float* __restrict__ wa,
                                                   const float* __restrict__ wp,
                                                   u16* __restrict__ xb,
                                                   u16* __restrict__ waT,
                                                   u16* __restrict__ wpT) {
  const int bx = blockIdx.x, t = threadIdx.x;
  if (bx < NCAST) {
    int i = bx * 256 + t;
    float4 v = ((const float4*)x)[i];
    ushort4 o = {f2bf(v.x), f2bf(v.y), f2bf(v.z), f2bf(v.w)};
    ((ushort4*)xb)[i] = o;
    return;
  }
  __shared__ float tile[32][33];
  const float* W;
  u16* WT;
  int N, idx;
  if (bx < NCAST + NTA) {
    W = wa; WT = waT; N = 3 * Cz; idx = bx - NCAST;
  } else {
    W = wp; WT = wpT; N = Cz; idx = bx - NCAST - NTA;
  }
  const int n0 = (idx % (N / 32)) * 32, k0 = (idx / (N / 32)) * 32;
  const int tx = t & 31, ty = t >> 5;  // (32, 8)
#pragma unroll
  for (int i = 0; i < 4; ++i)
    tile[ty + 8 * i][tx] = W[(size_t)(k0 + ty + 8 * i) * N + n0 + tx];
  __syncthreads();
#pragma unroll
  for (int i = 0; i < 4; ++i)
    WT[(size_t)(n0 + ty + 8 * i) * Cz + k0 + tx] = f2bf(tile[tx][ty + 8 * i]);
}

// ---------- C[M][N] = A[M][K]*BT[N][K]^T + bias; 128xTN tile ----------
// cols < qcols get (acc+bias)*qscale (pre-scales q for attn exp2).
template <bool OUT_BF16, int TN>
__global__ __launch_bounds__(256) void gemm_bt(const u16* __restrict__ A,
                                               const u16* __restrict__ BT,
                                               const float* __restrict__ bias,
                                               void* __restrict__ Cout,
                                               int M, int N, int K,
                                               int qcols, float qscale) {
  __shared__ __align__(16) u16 As[128 * 32];
  __shared__ __align__(16) u16 Bs[TN * 32];
  constexpr int NT = TN / 32;
  const int t = threadIdx.x;
  const int wave = t >> 6, lane = t & 63;
  const int lm = lane & 15, lg = lane >> 4;
  const int wm = wave >> 1, wn = wave & 1;
  const int m0 = blockIdx.y * 128, n0 = blockIdx.x * TN;

  const int srow_in = lane >> 2;
  const int gseg = (lane & 3) ^ ((lane >> 3) & 3);  // XOR col-seg swizzle
  const size_t a_off0 = (size_t)(m0 + 32 * wave + srow_in) * K + gseg * 8;
  const size_t a_off1 = a_off0 + 16 * (size_t)K;
  u16* asl0 = &As[(32 * wave) * 32];
  u16* asl1 = &As[(32 * wave + 16) * 32];
  size_t b_off0 = 0, b_off1 = 0;
  u16 *bsl0, *bsl1 = nullptr;
  if constexpr (TN == 128) {
    b_off0 = (size_t)(n0 + 32 * wave + srow_in) * K + gseg * 8;
    b_off1 = b_off0 + 16 * (size_t)K;
    bsl0 = &Bs[(32 * wave) * 32];
    bsl1 = &Bs[(32 * wave + 16) * 32];
  } else {
    b_off0 = (size_t)(n0 + 16 * wave + srow_in) * K + gseg * 8;
    bsl0 = &Bs[(16 * wave) * 32];
  }
  const int rseg = (lg ^ ((lm >> 1) & 3)) * 8;

  f32x4 acc[4][NT];
#pragma unroll
  for (int mt = 0; mt < 4; ++mt)
#pragma unroll
    for (int nt = 0; nt < NT; ++nt)
#pragma unroll
      for (int i = 0; i < 4; ++i) acc[mt][nt][i] = 0.f;

  for (int k0 = 0; k0 < K; k0 += 32) {
    __syncthreads();
    gl_lds16(A + a_off0 + k0, asl0);
    gl_lds16(A + a_off1 + k0, asl1);
    gl_lds16(BT + b_off0 + k0, bsl0);
    if constexpr (TN == 128) gl_lds16(BT + b_off1 + k0, bsl1);
    __syncthreads();

    bf16x8 af[4], bfr[NT];
#pragma unroll
    for (int mt = 0; mt < 4; ++mt)
      af[mt] = *(const bf16x8*)&As[(64 * wm + 16 * mt + lm) * 32 + rseg];
#pragma unroll
    for (int nt = 0; nt < NT; ++nt)
      bfr[nt] = *(const bf16x8*)&Bs[((TN / 2) * wn + 16 * nt + lm) * 32 + rseg];
#pragma unroll
    for (int mt = 0; mt < 4; ++mt)
#pragma unroll
      for (int nt = 0; nt < NT; ++nt)
        acc[mt][nt] = __builtin_amdgcn_mfma_f32_16x16x32_bf16(af[mt], bfr[nt],
                                                              acc[mt][nt], 0, 0, 0);
  }

#pragma unroll
  for (int nt = 0; nt < NT; ++nt) {
    int gc = n0 + (TN / 2) * wn + 16 * nt + lm;
    float bv = bias[gc];
    float sc = (gc < qcols) ? qscale : 1.f;
#pragma unroll
    for (int mt = 0; mt < 4; ++mt) {
#pragma unroll
      for (int i = 0; i < 4; ++i) {
        int gr = m0 + 64 * wm + 16 * mt + 4 * lg + i;
        float v = (acc[mt][nt][i] + bv) * sc;
        if (OUT_BF16)
          ((u16*)Cout)[(size_t)gr * N + gc] = f2bf(v);
        else
          ((float*)Cout)[(size_t)gr * N + gc] = v;
      }
    }
  }
}

// ---------------- flash attention, MFMA bf16, m=0 softmax ----------------
// 1D grid of 1024: x = qtp*32 + bh -> blockIdx%8 == bh%8 (XCD L2 affinity).
// CU-balanced qt map: qt = qtp<16 ? qtp : 47-qtp. Round-robin block->CU gives
// CU class a the qtps {a,a+8,a+16,a+24} -> qts {a,a+8,31-a,23-a}, total work
// = 62 units for EVERY class (the old pair-swizzle varied 28..104 -> 24% occ).
// 4 waves; wave w owns Q-rows [64qt+16w,+16). 2-deep register prefetch.
// p = exp2(S) (q pre-scaled), l deferred to epilogue butterfly. Epilogue
// bounces O through wave-private Ps rows for 16B coalesced stores.
__global__ __launch_bounds__(256) void attn_kernel(const u16* __restrict__ qkv,
                                                   u16* __restrict__ yb) {
  __shared__ __align__(16) u16 Ks[64][72];
  __shared__ __align__(16) u16 Vt[64][72];
  __shared__ __align__(16) u16 Ps[64][72];

  const int t = threadIdx.x;
  const int wave = t >> 6, lane = t & 63;
  const int lm = lane & 15, lg = lane >> 4;
  const int kg8 = lg << 3;
  const int x = blockIdx.x;
  const int bh = x & 31, qtp = x >> 5;
  const int qt = (qtp < 16) ? qtp : 47 - qtp;  // CU-balanced map
  const int b = bh >> 4, h = bh & 15;
  const int q0 = qt * 64;
  const size_t rowstride = 3 * Cz;
  const u16* qbase = qkv + (size_t)b * Tz * rowstride + h * Dz;

  bf16x8 qf[2];
  {
    const u16* qrow = qbase + (size_t)(q0 + wave * 16 + lm) * rowstride + kg8;
    qf[0] = *(const bf16x8*)qrow;
    qf[1] = *(const bf16x8*)(qrow + 32);
  }

  float psum[4];
  f32x4 Oa[4];
#pragma unroll
  for (int i = 0; i < 4; ++i) {
    psum[i] = 0.f;
#pragma unroll
    for (int j = 0; j < 4; ++j) Oa[i][j] = 0.f;
  }

  // per-thread staging offsets
  const int ksr = t >> 2, kds = (t & 3) << 4;   // K: row, 16-col seg
  const int vsp = t & 31, vds = (t >> 5) << 3;  // V: s-pair, 8-d seg
  const u16* kbase = qbase + Cz + (size_t)ksr * rowstride + kds;
  const u16* vbase = qbase + 2 * Cz + (size_t)(2 * vsp) * rowstride + vds;
  const size_t tilestep = 64 * rowstride;

  uint4 krA[2], vrA[2], krB[2], vrB[2];
  {  // prologue: prefetch tiles 0 and min(1,qt)
    const u16* kp = kbase;
    const u16* vp = vbase;
    krA[0] = *(const uint4*)kp;
    krA[1] = *(const uint4*)(kp + 8);
    vrA[0] = *(const uint4*)vp;
    vrA[1] = *(const uint4*)(vp + rowstride);
    const int t1 = (qt >= 1) ? 1 : 0;
    kp = kbase + (size_t)t1 * tilestep;
    vp = vbase + (size_t)t1 * tilestep;
    krB[0] = *(const uint4*)kp;
    krB[1] = *(const uint4*)(kp + 8);
    vrB[0] = *(const uint4*)vp;
    vrB[1] = *(const uint4*)(vp + rowstride);
  }

  auto stage = [&](uint4 (&kr)[2], uint4 (&vr)[2], int ktc) {
    __syncthreads();  // prior stage's Ks/Vt reads complete
    *(uint4*)&Ks[ksr][kds] = kr[0];
    *(uint4*)&Ks[ksr][kds + 8] = kr[1];
    {
      unsigned av[4] = {vr[0].x, vr[0].y, vr[0].z, vr[0].w};
      unsigned cv[4] = {vr[1].x, vr[1].y, vr[1].z, vr[1].w};
#pragma unroll
      for (int j = 0; j < 4; ++j) {
        unsigned w0 = (av[j] & 0xffffu) | (cv[j] << 16);
        unsigned w1 = (av[j] >> 16) | (cv[j] & 0xffff0000u);
        *(unsigned*)&Vt[vds + 2 * j][2 * vsp] = w0;
        *(unsigned*)&Vt[vds + 2 * j + 1][2 * vsp] = w1;
      }
    }
    __syncthreads();

    // prefetch tile ktc+2 into this stage's regs (skip past-end: regs unused)
    if (ktc + 2 <= qt) {
      const u16* kp = kbase + (size_t)(ktc + 2) * tilestep;
      const u16* vp = vbase + (size_t)(ktc + 2) * tilestep;
      kr[0] = *(const uint4*)kp;
      kr[1] = *(const uint4*)(kp + 8);
      vr[0] = *(const uint4*)vp;
      vr[1] = *(const uint4*)(vp + rowstride);
    }

    // ---- S = Q K^T (pre-scaled) ----
    f32x4 S[4];
#pragma unroll
    for (int c = 0; c < 4; ++c) {
      bf16x8 k0 = *(const bf16x8*)&Ks[c * 16 + lm][kg8];
      bf16x8 k1 = *(const bf16x8*)&Ks[c * 16 + lm][32 + kg8];
      f32x4 s;
#pragma unroll
      for (int i = 0; i < 4; ++i) s[i] = 0.f;
      s = __builtin_amdgcn_mfma_f32_16x16x32_bf16(qf[0], k0, s, 0, 0, 0);
      s = __builtin_amdgcn_mfma_f32_16x16x32_bf16(qf[1], k1, s, 0, 0, 0);
      S[c] = s;
    }

    // ---- p = exp2(S), diag mask, accumulate l, write P ----
    const bool diag = (ktc == qt);
#pragma unroll
    for (int c = 0; c < 4; ++c) {
#pragma unroll
      for (int r = 0; r < 4; ++r) {
        float p = fexp2(S[c][r]);
        if (diag && (c * 16 + lm) > (16 * wave + 4 * lg + r)) p = 0.f;
        psum[r] += p;
        Ps[16 * wave + 4 * lg + r][c * 16 + lm] = f2bf(p);
      }
    }

    // ---- O += P V ----
    bf16x8 pf0 = *(const bf16x8*)&Ps[16 * wave + lm][kg8];
    bf16x8 pf1 = *(const bf16x8*)&Ps[16 * wave + lm][32 + kg8];
#pragma unroll
    for (int c = 0; c < 4; ++c) {
      bf16x8 v0 = *(const bf16x8*)&Vt[c * 16 + lm][kg8];
      bf16x8 v1 = *(const bf16x8*)&Vt[c * 16 + lm][32 + kg8];
      Oa[c] = __builtin_amdgcn_mfma_f32_16x16x32_bf16(pf0, v0, Oa[c], 0, 0, 0);
      Oa[c] = __builtin_amdgcn_mfma_f32_16x16x32_bf16(pf1, v1, Oa[c], 0, 0, 0);
    }
  };

  for (int kt = 0; kt <= qt; kt += 2) {
    stage(krA, vrA, kt);
    if (kt + 1 <= qt) stage(krB, vrB, kt + 1);
  }

  // ---- epilogue: l-reduction, normalize, bounce via Ps, coalesced store ----
  float inv[4];
#pragma unroll
  for (int r = 0; r < 4; ++r) {
    float s = psum[r];
#pragma unroll
    for (int msk = 1; msk < 16; msk <<= 1) s += __shfl_xor(s, msk);
    inv[r] = 1.f / s;
  }
  // Ps rows [16w,16w+16) are wave-private: no barrier needed
#pragma unroll
  for (int c = 0; c < 4; ++c)
#pragma unroll
    for (int r = 0; r < 4; ++r)
      Ps[16 * wave + 4 * lg + r][c * 16 + lm] = f2bf(Oa[c][r] * inv[r]);

  {
    const int row = lane >> 2, seg = lane & 3;
    const uint4* src = (const uint4*)&Ps[16 * wave + row][seg * 16];
    uint4 v0 = src[0];
    uint4 v1 = src[1];
    u16* dst = yb + (size_t)(b * Tz + q0 + 16 * wave + row) * Cz + h * Dz + seg * 16;
    *(uint4*)dst = v0;
    *(uint4*)(dst + 8) = v1;
  }
}

extern "C" void kernel_launch(void* const* d_in, const int* in_sizes, int n_in,
                              void* d_out, int out_size, void* d_ws, size_t ws_size,
                              hipStream_t stream) {
  const float* x      = (const float*)d_in[0];
  const float* w_attn = (const float*)d_in[1];
  const float* b_attn = (const float*)d_in[2];
  const float* w_proj = (const float*)d_in[3];
  const float* b_proj = (const float*)d_in[4];

  char* ws = (char*)d_ws;
  u16* xb   = (u16*)(ws);                        //  8 MB: x bf16 [4096,1024]
  u16* waT  = (u16*)(ws + (8ull << 20));         //  6 MB: w_attn^T bf16 [3072,1024]
  u16* wpT  = (u16*)(ws + (14ull << 20));        //  2 MB: w_proj^T bf16 [1024,1024]
  u16* qkvb = (u16*)(ws + (16ull << 20));        // 24 MB: qkv bf16 (q pre-scaled)
  u16* yb   = (u16*)(ws + (40ull << 20));        //  8 MB: y bf16 [4096,1024]

  const int M = Bz * Tz;  // 4096

  prep_kernel<<<NCAST + NTA + 1024, 256, 0, stream>>>(x, w_attn, w_proj, xb, waT, wpT);
  gemm_bt<true, 128><<<dim3(3 * Cz / 128, M / 128), 256, 0, stream>>>(
      xb, waT, b_attn, qkvb, M, 3 * Cz, Cz, Cz, QSCALE);
  attn_kernel<<<1024, 256, 0, stream>>>(qkvb, yb);
  gemm_bt<false, 64><<<dim3(Cz / 64, M / 128), 256, 0, stream>>>(
      yb, wpT, b_proj, d_out, M, Cz, Cz, 0, 1.f);
}